// Round 4
// baseline (384.739 us; speedup 1.0000x reference)
//
#include <hip/hip_runtime.h>
#include <hip/hip_bf16.h>

#define BATCH 4
#define SEQ   2048
#define DMODEL 1024
#define NHEAD 16
#define HS    64
#define MROWS (BATCH*SEQ)     // 8192
#define KDIM  DMODEL
#define NDIM  DMODEL

typedef short bf16x8 __attribute__((ext_vector_type(8)));
typedef float f32x4  __attribute__((ext_vector_type(4)));
typedef int   i32x2  __attribute__((ext_vector_type(2)));
typedef unsigned u32x4 __attribute__((ext_vector_type(4)));

#if __has_builtin(__builtin_amdgcn_exp2f)
#define EXP2(x) __builtin_amdgcn_exp2f(x)
#else
#define EXP2(x) exp2f(x)
#endif

static __device__ __forceinline__ unsigned short f2bf(float f) {
    union { float f; unsigned int u; } v; v.f = f;
    unsigned int r = (v.u + 0x7fffu + ((v.u >> 16) & 1u)) >> 16;
    return (unsigned short)r;
}

// two f32 -> packed bf16 (RNE) — emits v_cvt_pk_bf16_f32 on gfx950
static __device__ __forceinline__ unsigned int pk_bf16(float a, float b) {
    union { __hip_bfloat162 h; unsigned int u; } c;
    c.h = __float22bfloat162_rn(make_float2(a, b));
    return c.u;
}

// cross-lane half-swaps (gfx950). After pl32: a={a[0:31],b[0:31]}, b={a[32:63],b[32:63]}.
// After pl16: a'={a[0:15],b[0:15],a[32:47],b[32:47]}, b'={a[16:31],b[16:31],a[48:63],b[48:63]}.
static __device__ __forceinline__ void pl32swap(unsigned &a, unsigned &b) {
#if __has_builtin(__builtin_amdgcn_permlane32_swap)
    i32x2 r = __builtin_amdgcn_permlane32_swap((int)a, (int)b, false, false);
    a = (unsigned)r[0]; b = (unsigned)r[1];
#else
    asm volatile("v_permlane32_swap_b32 %0, %1" : "+v"(a), "+v"(b));
#endif
}
static __device__ __forceinline__ void pl16swap(unsigned &a, unsigned &b) {
#if __has_builtin(__builtin_amdgcn_permlane16_swap)
    i32x2 r = __builtin_amdgcn_permlane16_swap((int)a, (int)b, false, false);
    a = (unsigned)r[0]; b = (unsigned)r[1];
#else
    asm volatile("v_permlane16_swap_b32 %0, %1" : "+v"(a), "+v"(b));
#endif
}

// async global->LDS, 16 B per lane. LDS dest must be linear in lane (wave-uniform base + lane*16).
static __device__ __forceinline__ void gl2lds16(const void* g, void* l) {
    __builtin_amdgcn_global_load_lds((const __attribute__((address_space(1))) unsigned int*)g,
                                     (__attribute__((address_space(3))) unsigned int*)l, 16, 0, 0);
}

// ---------------- conversion kernels ----------------
__global__ __launch_bounds__(256) void cvt_bf16(const float* __restrict__ in,
                                                unsigned short* __restrict__ out) {
    int i = blockIdx.x * 256 + threadIdx.x;
    float4 v = ((const float4*)in)[i];
    ushort4 o;
    o.x = f2bf(v.x); o.y = f2bf(v.y); o.z = f2bf(v.z); o.w = f2bf(v.w);
    ((ushort4*)out)[i] = o;
}

// 4x 1024x1024 fp32 -> bf16 transposed, one launch (z selects matrix)
__global__ __launch_bounds__(256) void transpose_cvt4(const float* __restrict__ s0, const float* __restrict__ s1,
                                                      const float* __restrict__ s2, const float* __restrict__ s3,
                                                      unsigned short* __restrict__ d0, unsigned short* __restrict__ d1,
                                                      unsigned short* __restrict__ d2, unsigned short* __restrict__ d3) {
    const float* in; unsigned short* out;
    switch (blockIdx.z) {
        case 0:  in = s0; out = d0; break;
        case 1:  in = s1; out = d1; break;
        case 2:  in = s2; out = d2; break;
        default: in = s3; out = d3; break;
    }
    __shared__ float t[32][33];
    int tx = threadIdx.x, ty = threadIdx.y;          // (32,8)
    int x = blockIdx.x * 32 + tx;
    #pragma unroll
    for (int i = 0; i < 4; ++i) {
        int y = blockIdx.y * 32 + ty + i * 8;
        t[ty + i * 8][tx] = in[(size_t)y * 1024 + x];
    }
    __syncthreads();
    int x2 = blockIdx.y * 32 + tx;
    #pragma unroll
    for (int i = 0; i < 4; ++i) {
        int y2 = blockIdx.x * 32 + ty + i * 8;
        out[(size_t)y2 * 1024 + x2] = f2bf(t[tx][ty + i * 8]);
    }
}

// ---------------- GEMM core (m97 recipe) ----------------
// 128x128 tile, BK=64, global_load_lds width=16, XOR-swizzled LDS (2-way = free).
// Sm is one 32 KB buffer (As|Bs) so epilogues can reuse it for repacking.
// GEMM_DECLS once per kernel (single shared alloc); GEMM_KLOOP(TRANS) per path:
//   TRANS=0 -> C = x·W^T tile (C rows = x-rows);
//   TRANS=1 -> C^T (A-operand = W-frags; acc regs run along W-cols e; lanes = x-rows t).
#define GEMM_DECLS                                                                      \
    __shared__ __align__(16) short Sm[2 * 128 * 64];                                    \
    short* As = Sm;                                                                     \
    short* Bs = Sm + 128 * 64;                                                          \
    const int tid  = threadIdx.x;                                                       \
    const int lane = tid & 63;                                                          \
    const int w    = tid >> 6;                                                          \
    const int wm   = w >> 1, wn = w & 1;                                                \
    const int cc   = lane & 15, quad = lane >> 4;                                       \
    const int bn   = blockIdx.x;                                                        \
    const int bm   = blockIdx.y;                                                        \
    f32x4 acc[4][4] = {};

#define GEMM_KLOOP(TRANS)                                                               \
    {                                                                                   \
    const unsigned short* Ab = A  + (size_t)bm * 128 * KDIM;                            \
    const unsigned short* Bb = Bt + (size_t)bn * 128 * KDIM;                            \
    for (int kb = 0; kb < KDIM; kb += 64) {                                             \
        __syncthreads();                                                                \
        _Pragma("unroll")                                                               \
        for (int i = 0; i < 4; ++i) {                                                   \
            int S = (i * 4 + w) * 64 + lane;                                            \
            int r = S >> 3, g = (S & 7) ^ (r & 7);                                      \
            gl2lds16(Ab + (size_t)r * KDIM + kb + g * 8, (void*)&As[S * 8]);            \
            gl2lds16(Bb + (size_t)r * KDIM + kb + g * 8, (void*)&Bs[S * 8]);            \
        }                                                                               \
        asm volatile("s_waitcnt vmcnt(0)");                                             \
        __syncthreads();                                                                \
        _Pragma("unroll")                                                               \
        for (int kh = 0; kh < 2; ++kh) {                                                \
            bf16x8 xf[4], wf[4];                                                        \
            _Pragma("unroll")                                                           \
            for (int mt = 0; mt < 4; ++mt) {                                            \
                int r = wm * 64 + mt * 16 + cc;                                         \
                xf[mt] = *(const bf16x8*)&As[r * 64 + ((kh * 4 + quad) ^ (r & 7)) * 8]; \
            }                                                                           \
            _Pragma("unroll")                                                           \
            for (int nt = 0; nt < 4; ++nt) {                                            \
                int r = wn * 64 + nt * 16 + cc;                                         \
                wf[nt] = *(const bf16x8*)&Bs[r * 64 + ((kh * 4 + quad) ^ (r & 7)) * 8]; \
            }                                                                           \
            _Pragma("unroll")                                                           \
            for (int mt = 0; mt < 4; ++mt)                                              \
                _Pragma("unroll")                                                       \
                for (int nt = 0; nt < 4; ++nt)                                          \
                    acc[mt][nt] = (TRANS)                                               \
                      ? __builtin_amdgcn_mfma_f32_16x16x32_bf16(wf[nt], xf[mt], acc[mt][nt], 0, 0, 0) \
                      : __builtin_amdgcn_mfma_f32_16x16x32_bf16(xf[mt], wf[nt], acc[mt][nt], 0, 0, 0); \
        }                                                                               \
    }                                                                                   \
    }

// Merged QKV GEMM. Bt = [Wq|Wk|Wv] transposed, contiguous (3072 rows x 1024).
// grid (24, 64): bn 0..7 = Q (transposed acc, scaled), 8..15 = K (transposed acc),
//                16..23 = V (normal acc, V^T repack). Branches are block-uniform.
__global__ __launch_bounds__(256, 3) void gemm_qkv(const unsigned short* __restrict__ A,
                                                   const unsigned short* __restrict__ Bt,
                                                   unsigned short* __restrict__ Qo,
                                                   unsigned short* __restrict__ Ko,
                                                   unsigned short* __restrict__ Vo) {
    GEMM_DECLS
    if (bn < 16) {
        GEMM_KLOOP(1)
        // lane holds e = wn*64+nt*16+quad*4+r, t = wm*64+mt*16+cc. Repack via LDS,
        // fully-coalesced 16B/lane stores to (B,H,T,hs).
        const bool isK = bn >= 8;
        const float scale = isK ? 1.0f : 0.125f * 1.44269504f;   // hs^-0.5 * log2(e) for Q
        unsigned short* outp = isK ? Ko : Qo;
        __syncthreads();     // staging reads done; reuse Sm as [t 128][e 128] shorts
        #pragma unroll
        for (int mt = 0; mt < 4; ++mt) {
            #pragma unroll
            for (int nt = 0; nt < 4; ++nt) {
                int t  = wm * 64 + mt * 16 + cc;
                int e0 = wn * 64 + nt * 16 + quad * 4;
                uint2 pu;
                pu.x = pk_bf16(acc[mt][nt][0] * scale, acc[mt][nt][1] * scale);
                pu.y = pk_bf16(acc[mt][nt][2] * scale, acc[mt][nt][3] * scale);
                int sp = (e0 >> 2) ^ (t & 31);
                *(uint2*)&Sm[t * 128 + sp * 4] = pu;
            }
        }
        __syncthreads();
        const int h0 = (bn & 7) * 2;
        const int b  = bm >> 4;
        const int t0 = (bm & 15) * 128;
        #pragma unroll
        for (int i = 0; i < 8; ++i) {
            int s = i * 256 + tid;
            int t = s >> 4, g = s & 15;                 // 16-lane groups share t
            int sp0 = (2 * g)     ^ (t & 31);
            int sp1 = (2 * g + 1) ^ (t & 31);
            uint2 lo = *(const uint2*)&Sm[t * 128 + sp0 * 4];
            uint2 hi = *(const uint2*)&Sm[t * 128 + sp1 * 4];
            int h = h0 + (g >> 3), e = (g & 7) * 8;
            size_t addr = ((size_t)(b * NHEAD + h) * SEQ + t0 + t) * HS + e;
            uint4 u; u.x = lo.x; u.y = lo.y; u.z = hi.x; u.w = hi.y;
            *(uint4*)&outp[addr] = u;
        }
    } else {
        GEMM_KLOOP(0)
        // V: repack through LDS, store V^T (B,H,hs,T) coalesced.
        __syncthreads();
        #pragma unroll
        for (int mt = 0; mt < 4; ++mt) {
            #pragma unroll
            for (int nt = 0; nt < 4; ++nt) {
                int n    = wn * 64 + nt * 16 + cc;            // col in tile (e-dim)
                int slot = wm * 16 + mt * 4 + quad;           // t/4 (4 rows per 8B slot)
                int sp   = slot ^ (n & 31);
                uint2 pu;
                pu.x = pk_bf16(acc[mt][nt][0], acc[mt][nt][1]);
                pu.y = pk_bf16(acc[mt][nt][2], acc[mt][nt][3]);
                *(uint2*)&Sm[n * 128 + sp * 4] = pu;
            }
        }
        __syncthreads();
        const int h0 = (bn & 7) * 2;
        const int b  = bm >> 4;
        const int t0 = (bm & 15) * 128;
        #pragma unroll
        for (int i = 0; i < 8; ++i) {
            int s = i * 256 + tid;
            int n = s >> 4, g = s & 15;
            int sp0 = (2 * g)     ^ (n & 31);
            int sp1 = (2 * g + 1) ^ (n & 31);
            uint2 lo = *(const uint2*)&Sm[n * 128 + sp0 * 4];
            uint2 hi = *(const uint2*)&Sm[n * 128 + sp1 * 4];
            int h = h0 + (n >> 6), e = n & 63;
            size_t addr = ((size_t)((b * NHEAD + h) * HS + e)) * SEQ + t0 + g * 8;
            uint4 u; u.x = lo.x; u.y = lo.y; u.z = hi.x; u.w = hi.y;
            *(uint4*)&Vo[addr] = u;
        }
    }
}

// Output projection: C[M,N] fp32 = A @ Wp (+bias)
__global__ __launch_bounds__(256, 3) void gemm_proj(const unsigned short* __restrict__ A,
                                                    const unsigned short* __restrict__ Bt,
                                                    float* __restrict__ Cout,
                                                    const float* __restrict__ bias) {
    GEMM_DECLS
    GEMM_KLOOP(0)
    #pragma unroll
    for (int mt = 0; mt < 4; ++mt) {
        #pragma unroll
        for (int nt = 0; nt < 4; ++nt) {
            f32x4 a = acc[mt][nt];
            int gn  = bn * 128 + wn * 64 + nt * 16 + cc;
            int gm0 = bm * 128 + wm * 64 + mt * 16 + quad * 4;
            #pragma unroll
            for (int r = 0; r < 4; ++r)
                Cout[(size_t)(gm0 + r) * NDIM + gn] = a[r] + bias[gn];
        }
    }
}

// ---------------- flash attention (transposed-S, in-register P, shift-free softmax) --
// Q,K: (B,H,T,hs) bf16 (Q pre-scaled by 0.125*log2e); Vt: (B,H,hs,T) bf16; O: (B,T,H*hs) bf16.
// Grid: x = bh (fast dim -> same bh pinned to one XCD via id%8), y = q-block (heavy-first).
// S^T = K*Q^T -> per lane: q = lane&15, 32 key-scores in regs.  O^T = V*P^T.
// r11: T12 in-register P (cvtpk + permlane32/16 swaps), bank conflicts -> 0.
// r12 (this round): SINGLE-buffer K/V staging, occupancy 2 -> 4+ blocks/CU.
//   r2 proved the double-buffer neutral: cross-block wave overlap already hides the
//   vmcnt(0) drain at 2 blocks/CU. So the 2nd buffer pays 32 KB LDS for nothing.
//   Single 32 KB buffer + __launch_bounds__(256,4) (VGPR cap 128 >= current 100,
//   no r9-style spill) doubles the resident-wave pool; per-trip staging latency is
//   covered by the other blocks' compute — same mechanism, 2x the headroom.
//   Structure per trip: STAGE -> vmcnt(0) -> s_barrier -> compute -> s_barrier.
//   (Second barrier: all waves' fragment reads are consumed by MFMAs before it, so
//   the next trip's restage cannot overwrite live data.)
__global__ __launch_bounds__(256, 4) void flash_attn(const unsigned short* __restrict__ Q,
                                                     const unsigned short* __restrict__ K,
                                                     const unsigned short* __restrict__ Vt,
                                                     unsigned short* __restrict__ O) {
    __shared__ __align__(16) short Ks[128 * 64];  // (key,hs) row=8 groups, slot g^(r&7)
    __shared__ __align__(16) short Vs[64 * 128];  // (d,key)  row=16 groups, slot g^(d&15)

    const int tid  = threadIdx.x;
    const int lane = tid & 63;
    const int w    = tid >> 6;
    const int cc   = lane & 15, quad = lane >> 4;
    const int bh   = blockIdx.x;                                     // 0..63
    const int qblk = ((int)gridDim.y - 1 - (int)blockIdx.y) * 128;   // heavy blocks first
    const int b    = bh >> 4, h = bh & 15;

    const unsigned short* Qb = Q  + (size_t)bh * SEQ * HS;
    const unsigned short* Kb = K  + (size_t)bh * SEQ * HS;
    const unsigned short* Vb = Vt + (size_t)bh * HS * SEQ;

    // Q fragments (B-operand), held in registers
    bf16x8 qf[2][2];
    #pragma unroll
    for (int qt = 0; qt < 2; ++qt) {
        int qg = qblk + w * 32 + qt * 16;
        const unsigned short* qp = Qb + (size_t)(qg + cc) * HS;
        qf[qt][0] = *(const bf16x8*)(qp + quad * 8);
        qf[qt][1] = *(const bf16x8*)(qp + 32 + quad * 8);
    }

    bf16x8 onesv;
    #pragma unroll
    for (int j = 0; j < 8; ++j) onesv[j] = (short)0x3F80;   // bf16 1.0

    f32x4 o[2][4] = {};
    f32x4 lacc[2] = {};
    const f32x4 zero = {};

    // 8 global_load_lds per wave per tile (4 K + 4 V), LDS dest linear in lane
#define STAGE_KV(kb_)                                                                   \
    _Pragma("unroll")                                                                   \
    for (int i = 0; i < 4; ++i) {                                                       \
        int S = (i * 4 + w) * 64 + lane;                                                \
        {   /* K tile: 128 keys x 64 hs */                                              \
            int r = S >> 3, g = (S & 7) ^ (r & 7);                                      \
            gl2lds16(Kb + (size_t)((kb_) + r) * HS + g * 8, (void*)&Ks[S * 8]);         \
        }                                                                               \
        {   /* V tile: 64 d x 128 keys */                                               \
            int d = S >> 4, g = (S & 15) ^ (d & 15);                                    \
            gl2lds16(Vb + (size_t)d * SEQ + (kb_) + g * 8, (void*)&Vs[S * 8]);          \
        }                                                                               \
    }

    const int trips = qblk / 128 + 1;
    for (int it = 0; it < trips; ++it) {
        const int kb = it * 128;

        STAGE_KV(kb)
        asm volatile("s_waitcnt vmcnt(0)" ::: "memory");
        __builtin_amdgcn_s_barrier();                // tile resident for all waves
        __builtin_amdgcn_sched_barrier(0);

        // ---- S^T = K·Q^T : kt-outer so each K-fragment read serves both q-tiles ----
        f32x4 st[2][8];
        #pragma unroll
        for (int kt = 0; kt < 8; ++kt) {
            int r = kt * 16 + cc;
            bf16x8 kf0 = *(const bf16x8*)&Ks[r * 64 + ((quad)     ^ (r & 7)) * 8];
            bf16x8 kf1 = *(const bf16x8*)&Ks[r * 64 + ((4 + quad) ^ (r & 7)) * 8];
            st[0][kt] = __builtin_amdgcn_mfma_f32_16x16x32_bf16(kf0, qf[0][0], zero,      0, 0, 0);
            st[0][kt] = __builtin_amdgcn_mfma_f32_16x16x32_bf16(kf1, qf[0][1], st[0][kt], 0, 0, 0);
            st[1][kt] = __builtin_amdgcn_mfma_f32_16x16x32_bf16(kf0, qf[1][0], zero,      0, 0, 0);
            st[1][kt] = __builtin_amdgcn_mfma_f32_16x16x32_bf16(kf1, qf[1][1], st[1][kt], 0, 0, 0);
        }

        // ---- mask + exp2 in place (st := P as f32) ----
        #pragma unroll
        for (int qt = 0; qt < 2; ++qt) {
            const int qg = qblk + w * 32 + qt * 16;
            // causal mask — needed whenever any key in the tile exceeds the SMALLEST q
            if (kb + 127 > qg) {
                #pragma unroll
                for (int kt = 0; kt < 8; ++kt)
                    #pragma unroll
                    for (int r = 0; r < 4; ++r)
                        if (kb + kt * 16 + quad * 4 + r > qg + cc) st[qt][kt][r] = -1e30f;
            }
            #pragma unroll
            for (int kt = 0; kt < 8; ++kt) {
                st[qt][kt][0] = EXP2(st[qt][kt][0]);
                st[qt][kt][1] = EXP2(st[qt][kt][1]);
                st[qt][kt][2] = EXP2(st[qt][kt][2]);
                st[qt][kt][3] = EXP2(st[qt][kt][3]);
            }
        }

        // ---- in-register P: cvtpk + permlane32/16 swaps; O^T += V·P^T; l += ones·P^T --
        #pragma unroll
        for (int k32 = 0; k32 < 4; ++k32) {
            bf16x8 pb[2];
            #pragma unroll
            for (int qt = 0; qt < 2; ++qt) {
                unsigned a0 = pk_bf16(st[qt][2 * k32][0],     st[qt][2 * k32][1]);
                unsigned a1 = pk_bf16(st[qt][2 * k32][2],     st[qt][2 * k32][3]);
                unsigned b0 = pk_bf16(st[qt][2 * k32 + 1][0], st[qt][2 * k32 + 1][1]);
                unsigned b1 = pk_bf16(st[qt][2 * k32 + 1][2], st[qt][2 * k32 + 1][3]);
                pl32swap(a0, b0); pl16swap(a0, b0);   // a0 = dword j(0,1), b0 = dword j(4,5)
                pl32swap(a1, b1); pl16swap(a1, b1);   // a1 = dword j(2,3), b1 = dword j(6,7)
                u32x4 pw; pw[0] = a0; pw[1] = a1; pw[2] = b0; pw[3] = b1;
                pb[qt] = __builtin_bit_cast(bf16x8, pw);
            }
            lacc[0] = __builtin_amdgcn_mfma_f32_16x16x32_bf16(onesv, pb[0], lacc[0], 0, 0, 0);
            lacc[1] = __builtin_amdgcn_mfma_f32_16x16x32_bf16(onesv, pb[1], lacc[1], 0, 0, 0);
            #pragma unroll
            for (int nt = 0; nt < 4; ++nt) {
                int d = nt * 16 + cc;
                bf16x8 vf = *(const bf16x8*)&Vs[d * 128 + ((k32 * 4 + quad) ^ (d & 15)) * 8];
                o[0][nt] = __builtin_amdgcn_mfma_f32_16x16x32_bf16(vf, pb[0], o[0][nt], 0, 0, 0);
                o[1][nt] = __builtin_amdgcn_mfma_f32_16x16x32_bf16(vf, pb[1], o[1][nt], 0, 0, 0);
            }
        }

        __builtin_amdgcn_sched_barrier(0);
        __builtin_amdgcn_s_barrier();                // all waves done reading before restage
    }

    // epilogue: lane holds O^T[d = nt*16 + quad*4 + r][q = cc]; l[q] = lacc[qt][any reg]
    #pragma unroll
    for (int qt = 0; qt < 2; ++qt) {
        int qg = qblk + w * 32 + qt * 16;
        float inv = 1.0f / lacc[qt][0];
        size_t base = ((size_t)b * SEQ + qg + cc) * DMODEL + h * HS;
        #pragma unroll
        for (int nt = 0; nt < 4; ++nt) {
            ushort4 u;
            u.x = f2bf(o[qt][nt][0] * inv);
            u.y = f2bf(o[qt][nt][1] * inv);
            u.z = f2bf(o[qt][nt][2] * inv);
            u.w = f2bf(o[qt][nt][3] * inv);
            *(ushort4*)&O[base + nt * 16 + quad * 4] = u;
        }
    }
}

// ---------------- launch ----------------
extern "C" void kernel_launch(void* const* d_in, const int* in_sizes, int n_in,
                              void* d_out, int out_size, void* d_ws, size_t ws_size,
                              hipStream_t stream) {
    const float* x  = (const float*)d_in[0];
    const float* Wq = (const float*)d_in[1];
    const float* Wk = (const float*)d_in[2];
    const float* Wv = (const float*)d_in[3];
    const float* Wp = (const float*)d_in[4];
    const float* bp = (const float*)d_in[5];
    float* out = (float*)d_out;

    char* ws = (char*)d_ws;
    unsigned short* xb    = (unsigned short*)(ws);                      // 16 MiB
    unsigned short* wqkvt = (unsigned short*)(ws + (16u << 20));        // 6 MiB (Q|K|V transposed)
    unsigned short* wpt   = (unsigned short*)(ws + (22u << 20));        // 2 MiB
    unsigned short* qws   = (unsigned short*)(ws + (24u << 20));        // 16 MiB
    unsigned short* kws   = (unsigned short*)(ws + (40u << 20));        // 16 MiB
    unsigned short* vtws  = (unsigned short*)(ws + (56u << 20));        // 16 MiB
    unsigned short* attn  = (unsigned short*)(ws + (72u << 20));        // 16 MiB

    cvt_bf16<<<MROWS * DMODEL / 1024, 256, 0, stream>>>(x, xb);

    transpose_cvt4<<<dim3(32, 32, 4), dim3(32, 8), 0, stream>>>(
        Wq, Wk, Wv, Wp, wqkvt, wqkvt + (1u << 20), wqkvt + (2u << 20), wpt);

    // merged Q/K/V GEMM: bn 0..7 = Q, 8..15 = K, 16..23 = V
    gemm_qkv<<<dim3(24, MROWS / 128), 256, 0, stream>>>(xb, wqkvt, qws, kws, vtws);

    // grid: x = bh (XCD-local K/V reuse), y = q-block index (heavy-first inside kernel)
    flash_attn<<<dim3(BATCH * NHEAD, SEQ / 128), 256, 0, stream>>>(qws, kws, vtws, attn);

    gemm_proj<<<dim3(NDIM / 128, MROWS / 128), 256, 0, stream>>>(attn, wpt, out, bp);
}

// Round 5
// 221.467 us; speedup vs baseline: 1.7372x; 1.7372x over previous
//
#include <hip/hip_runtime.h>
#include <hip/hip_bf16.h>

#define BATCH 4
#define SEQ   2048
#define DMODEL 1024
#define NHEAD 16
#define HS    64
#define MROWS (BATCH*SEQ)     // 8192
#define KDIM  DMODEL
#define NDIM  DMODEL

typedef short bf16x8 __attribute__((ext_vector_type(8)));
typedef float f32x4  __attribute__((ext_vector_type(4)));
typedef int   i32x2  __attribute__((ext_vector_type(2)));
typedef unsigned u32x4 __attribute__((ext_vector_type(4)));

#if __has_builtin(__builtin_amdgcn_exp2f)
#define EXP2(x) __builtin_amdgcn_exp2f(x)
#else
#define EXP2(x) exp2f(x)
#endif

static __device__ __forceinline__ unsigned short f2bf(float f) {
    union { float f; unsigned int u; } v; v.f = f;
    unsigned int r = (v.u + 0x7fffu + ((v.u >> 16) & 1u)) >> 16;
    return (unsigned short)r;
}

// two f32 -> packed bf16 (RNE) — emits v_cvt_pk_bf16_f32 on gfx950
static __device__ __forceinline__ unsigned int pk_bf16(float a, float b) {
    union { __hip_bfloat162 h; unsigned int u; } c;
    c.h = __float22bfloat162_rn(make_float2(a, b));
    return c.u;
}

// cross-lane half-swaps (gfx950). After pl32: a={a[0:31],b[0:31]}, b={a[32:63],b[32:63]}.
// After pl16: a'={a[0:15],b[0:15],a[32:47],b[32:47]}, b'={a[16:31],b[16:31],a[48:63],b[48:63]}.
static __device__ __forceinline__ void pl32swap(unsigned &a, unsigned &b) {
#if __has_builtin(__builtin_amdgcn_permlane32_swap)
    i32x2 r = __builtin_amdgcn_permlane32_swap((int)a, (int)b, false, false);
    a = (unsigned)r[0]; b = (unsigned)r[1];
#else
    asm volatile("v_permlane32_swap_b32 %0, %1" : "+v"(a), "+v"(b));
#endif
}
static __device__ __forceinline__ void pl16swap(unsigned &a, unsigned &b) {
#if __has_builtin(__builtin_amdgcn_permlane16_swap)
    i32x2 r = __builtin_amdgcn_permlane16_swap((int)a, (int)b, false, false);
    a = (unsigned)r[0]; b = (unsigned)r[1];
#else
    asm volatile("v_permlane16_swap_b32 %0, %1" : "+v"(a), "+v"(b));
#endif
}

// async global->LDS, 16 B per lane. LDS dest must be linear in lane (wave-uniform base + lane*16).
static __device__ __forceinline__ void gl2lds16(const void* g, void* l) {
    __builtin_amdgcn_global_load_lds((const __attribute__((address_space(1))) unsigned int*)g,
                                     (__attribute__((address_space(3))) unsigned int*)l, 16, 0, 0);
}

// ---------------- conversion kernels ----------------
__global__ __launch_bounds__(256) void cvt_bf16(const float* __restrict__ in,
                                                unsigned short* __restrict__ out) {
    int i = blockIdx.x * 256 + threadIdx.x;
    float4 v = ((const float4*)in)[i];
    ushort4 o;
    o.x = f2bf(v.x); o.y = f2bf(v.y); o.z = f2bf(v.z); o.w = f2bf(v.w);
    ((ushort4*)out)[i] = o;
}

// 4x 1024x1024 fp32 -> bf16 transposed, one launch (z selects matrix)
__global__ __launch_bounds__(256) void transpose_cvt4(const float* __restrict__ s0, const float* __restrict__ s1,
                                                      const float* __restrict__ s2, const float* __restrict__ s3,
                                                      unsigned short* __restrict__ d0, unsigned short* __restrict__ d1,
                                                      unsigned short* __restrict__ d2, unsigned short* __restrict__ d3) {
    const float* in; unsigned short* out;
    switch (blockIdx.z) {
        case 0:  in = s0; out = d0; break;
        case 1:  in = s1; out = d1; break;
        case 2:  in = s2; out = d2; break;
        default: in = s3; out = d3; break;
    }
    __shared__ float t[32][33];
    int tx = threadIdx.x, ty = threadIdx.y;          // (32,8)
    int x = blockIdx.x * 32 + tx;
    #pragma unroll
    for (int i = 0; i < 4; ++i) {
        int y = blockIdx.y * 32 + ty + i * 8;
        t[ty + i * 8][tx] = in[(size_t)y * 1024 + x];
    }
    __syncthreads();
    int x2 = blockIdx.y * 32 + tx;
    #pragma unroll
    for (int i = 0; i < 4; ++i) {
        int y2 = blockIdx.x * 32 + ty + i * 8;
        out[(size_t)y2 * 1024 + x2] = f2bf(t[tx][ty + i * 8]);
    }
}

// ---------------- GEMM core (m97 recipe) ----------------
// 128x128 tile, BK=64, global_load_lds width=16, XOR-swizzled LDS (2-way = free).
// Sm is one 32 KB buffer (As|Bs) so epilogues can reuse it for repacking.
// GEMM_DECLS once per kernel (single shared alloc); GEMM_KLOOP(TRANS) per path:
//   TRANS=0 -> C = x·W^T tile (C rows = x-rows);
//   TRANS=1 -> C^T (A-operand = W-frags; acc regs run along W-cols e; lanes = x-rows t).
#define GEMM_DECLS                                                                      \
    __shared__ __align__(16) short Sm[2 * 128 * 64];                                    \
    short* As = Sm;                                                                     \
    short* Bs = Sm + 128 * 64;                                                          \
    const int tid  = threadIdx.x;                                                       \
    const int lane = tid & 63;                                                          \
    const int w    = tid >> 6;                                                          \
    const int wm   = w >> 1, wn = w & 1;                                                \
    const int cc   = lane & 15, quad = lane >> 4;                                       \
    const int bn   = blockIdx.x;                                                        \
    const int bm   = blockIdx.y;                                                        \
    f32x4 acc[4][4] = {};

#define GEMM_KLOOP(TRANS)                                                               \
    {                                                                                   \
    const unsigned short* Ab = A  + (size_t)bm * 128 * KDIM;                            \
    const unsigned short* Bb = Bt + (size_t)bn * 128 * KDIM;                            \
    for (int kb = 0; kb < KDIM; kb += 64) {                                             \
        __syncthreads();                                                                \
        _Pragma("unroll")                                                               \
        for (int i = 0; i < 4; ++i) {                                                   \
            int S = (i * 4 + w) * 64 + lane;                                            \
            int r = S >> 3, g = (S & 7) ^ (r & 7);                                      \
            gl2lds16(Ab + (size_t)r * KDIM + kb + g * 8, (void*)&As[S * 8]);            \
            gl2lds16(Bb + (size_t)r * KDIM + kb + g * 8, (void*)&Bs[S * 8]);            \
        }                                                                               \
        asm volatile("s_waitcnt vmcnt(0)");                                             \
        __syncthreads();                                                                \
        _Pragma("unroll")                                                               \
        for (int kh = 0; kh < 2; ++kh) {                                                \
            bf16x8 xf[4], wf[4];                                                        \
            _Pragma("unroll")                                                           \
            for (int mt = 0; mt < 4; ++mt) {                                            \
                int r = wm * 64 + mt * 16 + cc;                                         \
                xf[mt] = *(const bf16x8*)&As[r * 64 + ((kh * 4 + quad) ^ (r & 7)) * 8]; \
            }                                                                           \
            _Pragma("unroll")                                                           \
            for (int nt = 0; nt < 4; ++nt) {                                            \
                int r = wn * 64 + nt * 16 + cc;                                         \
                wf[nt] = *(const bf16x8*)&Bs[r * 64 + ((kh * 4 + quad) ^ (r & 7)) * 8]; \
            }                                                                           \
            _Pragma("unroll")                                                           \
            for (int mt = 0; mt < 4; ++mt)                                              \
                _Pragma("unroll")                                                       \
                for (int nt = 0; nt < 4; ++nt)                                          \
                    acc[mt][nt] = (TRANS)                                               \
                      ? __builtin_amdgcn_mfma_f32_16x16x32_bf16(wf[nt], xf[mt], acc[mt][nt], 0, 0, 0) \
                      : __builtin_amdgcn_mfma_f32_16x16x32_bf16(xf[mt], wf[nt], acc[mt][nt], 0, 0, 0); \
        }                                                                               \
    }                                                                                   \
    }

// Merged QKV GEMM. Bt = [Wq|Wk|Wv] transposed, contiguous (3072 rows x 1024).
// grid (24, 64): bn 0..7 = Q (transposed acc, scaled), 8..15 = K (transposed acc),
//                16..23 = V (normal acc, V^T repack). Branches are block-uniform.
__global__ __launch_bounds__(256, 3) void gemm_qkv(const unsigned short* __restrict__ A,
                                                   const unsigned short* __restrict__ Bt,
                                                   unsigned short* __restrict__ Qo,
                                                   unsigned short* __restrict__ Ko,
                                                   unsigned short* __restrict__ Vo) {
    GEMM_DECLS
    if (bn < 16) {
        GEMM_KLOOP(1)
        // lane holds e = wn*64+nt*16+quad*4+r, t = wm*64+mt*16+cc. Repack via LDS,
        // fully-coalesced 16B/lane stores to (B,H,T,hs).
        const bool isK = bn >= 8;
        const float scale = isK ? 1.0f : 0.125f * 1.44269504f;   // hs^-0.5 * log2(e) for Q
        unsigned short* outp = isK ? Ko : Qo;
        __syncthreads();     // staging reads done; reuse Sm as [t 128][e 128] shorts
        #pragma unroll
        for (int mt = 0; mt < 4; ++mt) {
            #pragma unroll
            for (int nt = 0; nt < 4; ++nt) {
                int t  = wm * 64 + mt * 16 + cc;
                int e0 = wn * 64 + nt * 16 + quad * 4;
                uint2 pu;
                pu.x = pk_bf16(acc[mt][nt][0] * scale, acc[mt][nt][1] * scale);
                pu.y = pk_bf16(acc[mt][nt][2] * scale, acc[mt][nt][3] * scale);
                int sp = (e0 >> 2) ^ (t & 31);
                *(uint2*)&Sm[t * 128 + sp * 4] = pu;
            }
        }
        __syncthreads();
        const int h0 = (bn & 7) * 2;
        const int b  = bm >> 4;
        const int t0 = (bm & 15) * 128;
        #pragma unroll
        for (int i = 0; i < 8; ++i) {
            int s = i * 256 + tid;
            int t = s >> 4, g = s & 15;                 // 16-lane groups share t
            int sp0 = (2 * g)     ^ (t & 31);
            int sp1 = (2 * g + 1) ^ (t & 31);
            uint2 lo = *(const uint2*)&Sm[t * 128 + sp0 * 4];
            uint2 hi = *(const uint2*)&Sm[t * 128 + sp1 * 4];
            int h = h0 + (g >> 3), e = (g & 7) * 8;
            size_t addr = ((size_t)(b * NHEAD + h) * SEQ + t0 + t) * HS + e;
            uint4 u; u.x = lo.x; u.y = lo.y; u.z = hi.x; u.w = hi.y;
            *(uint4*)&outp[addr] = u;
        }
    } else {
        GEMM_KLOOP(0)
        // V: repack through LDS, store V^T (B,H,hs,T) coalesced.
        __syncthreads();
        #pragma unroll
        for (int mt = 0; mt < 4; ++mt) {
            #pragma unroll
            for (int nt = 0; nt < 4; ++nt) {
                int n    = wn * 64 + nt * 16 + cc;            // col in tile (e-dim)
                int slot = wm * 16 + mt * 4 + quad;           // t/4 (4 rows per 8B slot)
                int sp   = slot ^ (n & 31);
                uint2 pu;
                pu.x = pk_bf16(acc[mt][nt][0], acc[mt][nt][1]);
                pu.y = pk_bf16(acc[mt][nt][2], acc[mt][nt][3]);
                *(uint2*)&Sm[n * 128 + sp * 4] = pu;
            }
        }
        __syncthreads();
        const int h0 = (bn & 7) * 2;
        const int b  = bm >> 4;
        const int t0 = (bm & 15) * 128;
        #pragma unroll
        for (int i = 0; i < 8; ++i) {
            int s = i * 256 + tid;
            int n = s >> 4, g = s & 15;
            int sp0 = (2 * g)     ^ (n & 31);
            int sp1 = (2 * g + 1) ^ (n & 31);
            uint2 lo = *(const uint2*)&Sm[n * 128 + sp0 * 4];
            uint2 hi = *(const uint2*)&Sm[n * 128 + sp1 * 4];
            int h = h0 + (n >> 6), e = n & 63;
            size_t addr = ((size_t)((b * NHEAD + h) * HS + e)) * SEQ + t0 + g * 8;
            uint4 u; u.x = lo.x; u.y = lo.y; u.z = hi.x; u.w = hi.y;
            *(uint4*)&Vo[addr] = u;
        }
    }
}

// Output projection: C[M,N] fp32 = A @ Wp (+bias)
__global__ __launch_bounds__(256, 3) void gemm_proj(const unsigned short* __restrict__ A,
                                                    const unsigned short* __restrict__ Bt,
                                                    float* __restrict__ Cout,
                                                    const float* __restrict__ bias) {
    GEMM_DECLS
    GEMM_KLOOP(0)
    #pragma unroll
    for (int mt = 0; mt < 4; ++mt) {
        #pragma unroll
        for (int nt = 0; nt < 4; ++nt) {
            f32x4 a = acc[mt][nt];
            int gn  = bn * 128 + wn * 64 + nt * 16 + cc;
            int gm0 = bm * 128 + wm * 64 + mt * 16 + quad * 4;
            #pragma unroll
            for (int r = 0; r < 4; ++r)
                Cout[(size_t)(gm0 + r) * NDIM + gn] = a[r] + bias[gn];
        }
    }
}

// ---------------- flash attention (transposed-S, in-register P, fused per-group loop) --
// Q,K: (B,H,T,hs) bf16 (Q pre-scaled by 0.125*log2e); Vt: (B,H,hs,T) bf16; O: (B,T,H*hs) bf16.
// Grid: x = bh (fast dim -> same bh pinned to one XCD via id%8), y = q-block (heavy-first).
// S^T = K*Q^T -> per lane: q = lane&15, 32 key-scores in regs.  O^T = V*P^T.
// r11: T12 in-register P (cvtpk + permlane32/16 swaps), bank conflicts -> 0.
// r13 (this round):
//   (a) FUSED 32-key-group loop: QK(8 mfma) -> mask/exp(16) -> pack -> lacc+PV(10 mfma)
//       per group instead of phase-separated. Live score state drops st[2][8](32 regs)
//       -> s[2][2](16 regs); total est ~120 regs -> fits the 170-reg budget of
//       __launch_bounds__(256,3) WITHOUT spilling (r9/r12 spilled because the
//       phase-separated structure needs ~200). Fusion also lets QK of group g+1
//       issue under exp/pack of group g — fills dependency bubbles within a wave.
//   (b) SINGLE-buffer K/V (32 KB LDS) — r2 proved dbuf neutral (inter-block overlap
//       hides the vmcnt(0) drain); 32 KB enables 3 blocks/CU under (256,3).
//   (c) Diagonal-trip group skip: on the last trip (kb==qblk), group g of wave w is
//       fully causal-masked when g > w -> skip QK/exp/PV entirely (wave-uniform).
//   Spill tripwire: WRITE_SIZE must stay ~16 MB (r9: 92 MB, r12: 309 MB = spills).
__global__ __launch_bounds__(256, 3) void flash_attn(const unsigned short* __restrict__ Q,
                                                     const unsigned short* __restrict__ K,
                                                     const unsigned short* __restrict__ Vt,
                                                     unsigned short* __restrict__ O) {
    __shared__ __align__(16) short Ks[128 * 64];  // (key,hs) row=8 groups, slot g^(r&7)
    __shared__ __align__(16) short Vs[64 * 128];  // (d,key)  row=16 groups, slot g^(d&15)

    const int tid  = threadIdx.x;
    const int lane = tid & 63;
    const int w    = tid >> 6;
    const int cc   = lane & 15, quad = lane >> 4;
    const int bh   = blockIdx.x;                                     // 0..63
    const int qblk = ((int)gridDim.y - 1 - (int)blockIdx.y) * 128;   // heavy blocks first
    const int b    = bh >> 4, h = bh & 15;

    const unsigned short* Qb = Q  + (size_t)bh * SEQ * HS;
    const unsigned short* Kb = K  + (size_t)bh * SEQ * HS;
    const unsigned short* Vb = Vt + (size_t)bh * HS * SEQ;

    // Q fragments (B-operand), held in registers
    bf16x8 qf[2][2];
    #pragma unroll
    for (int qt = 0; qt < 2; ++qt) {
        int qg = qblk + w * 32 + qt * 16;
        const unsigned short* qp = Qb + (size_t)(qg + cc) * HS;
        qf[qt][0] = *(const bf16x8*)(qp + quad * 8);
        qf[qt][1] = *(const bf16x8*)(qp + 32 + quad * 8);
    }

    bf16x8 onesv;
    #pragma unroll
    for (int j = 0; j < 8; ++j) onesv[j] = (short)0x3F80;   // bf16 1.0

    f32x4 o[2][4] = {};
    f32x4 lacc[2] = {};
    const f32x4 zero = {};

    // 8 global_load_lds per wave per tile (4 K + 4 V), LDS dest linear in lane
#define STAGE_KV(kb_)                                                                   \
    _Pragma("unroll")                                                                   \
    for (int i = 0; i < 4; ++i) {                                                       \
        int S = (i * 4 + w) * 64 + lane;                                                \
        {   /* K tile: 128 keys x 64 hs */                                              \
            int r = S >> 3, g = (S & 7) ^ (r & 7);                                      \
            gl2lds16(Kb + (size_t)((kb_) + r) * HS + g * 8, (void*)&Ks[S * 8]);         \
        }                                                                               \
        {   /* V tile: 64 d x 128 keys */                                               \
            int d = S >> 4, g = (S & 15) ^ (d & 15);                                    \
            gl2lds16(Vb + (size_t)d * SEQ + (kb_) + g * 8, (void*)&Vs[S * 8]);          \
        }                                                                               \
    }

    const int trips = qblk / 128 + 1;
    for (int it = 0; it < trips; ++it) {
        const int kb = it * 128;

        STAGE_KV(kb)
        asm volatile("s_waitcnt vmcnt(0)" ::: "memory");
        __builtin_amdgcn_s_barrier();                // tile resident for all waves
        __builtin_amdgcn_sched_barrier(0);

        // ---- fused per-32-key-group: QK -> mask/exp -> pack -> lacc+PV ----
        #pragma unroll
        for (int g = 0; g < 4; ++g) {
            // fully-masked group (diagonal-trip tail): skip (wave-uniform branch)
            if (kb + g * 32 > qblk + w * 32 + 31) continue;

            f32x4 s[2][2];
            #pragma unroll
            for (int ktl = 0; ktl < 2; ++ktl) {
                int r = (2 * g + ktl) * 16 + cc;
                bf16x8 kf0 = *(const bf16x8*)&Ks[r * 64 + ((quad)     ^ (r & 7)) * 8];
                bf16x8 kf1 = *(const bf16x8*)&Ks[r * 64 + ((4 + quad) ^ (r & 7)) * 8];
                s[0][ktl] = __builtin_amdgcn_mfma_f32_16x16x32_bf16(kf0, qf[0][0], zero,      0, 0, 0);
                s[0][ktl] = __builtin_amdgcn_mfma_f32_16x16x32_bf16(kf1, qf[0][1], s[0][ktl], 0, 0, 0);
                s[1][ktl] = __builtin_amdgcn_mfma_f32_16x16x32_bf16(kf0, qf[1][0], zero,      0, 0, 0);
                s[1][ktl] = __builtin_amdgcn_mfma_f32_16x16x32_bf16(kf1, qf[1][1], s[1][ktl], 0, 0, 0);
            }

            bf16x8 pb[2];
            #pragma unroll
            for (int qt = 0; qt < 2; ++qt) {
                const int qg = qblk + w * 32 + qt * 16;
                if (kb + g * 32 + 31 > qg) {              // group overlaps diagonal
                    #pragma unroll
                    for (int ktl = 0; ktl < 2; ++ktl)
                        #pragma unroll
                        for (int r = 0; r < 4; ++r)
                            if (kb + (2 * g + ktl) * 16 + quad * 4 + r > qg + cc)
                                s[qt][ktl][r] = -1e30f;
                }
                #pragma unroll
                for (int ktl = 0; ktl < 2; ++ktl) {
                    s[qt][ktl][0] = EXP2(s[qt][ktl][0]);
                    s[qt][ktl][1] = EXP2(s[qt][ktl][1]);
                    s[qt][ktl][2] = EXP2(s[qt][ktl][2]);
                    s[qt][ktl][3] = EXP2(s[qt][ktl][3]);
                }
                unsigned a0 = pk_bf16(s[qt][0][0], s[qt][0][1]);
                unsigned a1 = pk_bf16(s[qt][0][2], s[qt][0][3]);
                unsigned b0 = pk_bf16(s[qt][1][0], s[qt][1][1]);
                unsigned b1 = pk_bf16(s[qt][1][2], s[qt][1][3]);
                pl32swap(a0, b0); pl16swap(a0, b0);   // a0 = dword j(0,1), b0 = dword j(4,5)
                pl32swap(a1, b1); pl16swap(a1, b1);   // a1 = dword j(2,3), b1 = dword j(6,7)
                u32x4 pw; pw[0] = a0; pw[1] = a1; pw[2] = b0; pw[3] = b1;
                pb[qt] = __builtin_bit_cast(bf16x8, pw);
            }

            lacc[0] = __builtin_amdgcn_mfma_f32_16x16x32_bf16(onesv, pb[0], lacc[0], 0, 0, 0);
            lacc[1] = __builtin_amdgcn_mfma_f32_16x16x32_bf16(onesv, pb[1], lacc[1], 0, 0, 0);
            #pragma unroll
            for (int nt = 0; nt < 4; ++nt) {
                int d = nt * 16 + cc;
                bf16x8 vf = *(const bf16x8*)&Vs[d * 128 + ((g * 4 + quad) ^ (d & 15)) * 8];
                o[0][nt] = __builtin_amdgcn_mfma_f32_16x16x32_bf16(vf, pb[0], o[0][nt], 0, 0, 0);
                o[1][nt] = __builtin_amdgcn_mfma_f32_16x16x32_bf16(vf, pb[1], o[1][nt], 0, 0, 0);
            }
        }

        __builtin_amdgcn_sched_barrier(0);
        __builtin_amdgcn_s_barrier();                // all waves done reading before restage
    }

    // epilogue: lane holds O^T[d = nt*16 + quad*4 + r][q = cc]; l[q] = lacc[qt][any reg]
    #pragma unroll
    for (int qt = 0; qt < 2; ++qt) {
        int qg = qblk + w * 32 + qt * 16;
        float inv = 1.0f / lacc[qt][0];
        size_t base = ((size_t)b * SEQ + qg + cc) * DMODEL + h * HS;
        #pragma unroll
        for (int nt = 0; nt < 4; ++nt) {
            ushort4 u;
            u.x = f2bf(o[qt][nt][0] * inv);
            u.y = f2bf(o[qt][nt][1] * inv);
            u.z = f2bf(o[qt][nt][2] * inv);
            u.w = f2bf(o[qt][nt][3] * inv);
            *(ushort4*)&O[base + nt * 16 + quad * 4] = u;
        }
    }
}

// ---------------- launch ----------------
extern "C" void kernel_launch(void* const* d_in, const int* in_sizes, int n_in,
                              void* d_out, int out_size, void* d_ws, size_t ws_size,
                              hipStream_t stream) {
    const float* x  = (const float*)d_in[0];
    const float* Wq = (const float*)d_in[1];
    const float* Wk = (const float*)d_in[2];
    const float* Wv = (const float*)d_in[3];
    const float* Wp = (const float*)d_in[4];
    const float* bp = (const float*)d_in[5];
    float* out = (float*)d_out;

    char* ws = (char*)d_ws;
    unsigned short* xb    = (unsigned short*)(ws);                      // 16 MiB
    unsigned short* wqkvt = (unsigned short*)(ws + (16u << 20));        // 6 MiB (Q|K|V transposed)
    unsigned short* wpt   = (unsigned short*)(ws + (22u << 20));        // 2 MiB
    unsigned short* qws   = (unsigned short*)(ws + (24u << 20));        // 16 MiB
    unsigned short* kws   = (unsigned short*)(ws + (40u << 20));        // 16 MiB
    unsigned short* vtws  = (unsigned short*)(ws + (56u << 20));        // 16 MiB
    unsigned short* attn  = (unsigned short*)(ws + (72u << 20));        // 16 MiB

    cvt_bf16<<<MROWS * DMODEL / 1024, 256, 0, stream>>>(x, xb);

    transpose_cvt4<<<dim3(32, 32, 4), dim3(32, 8), 0, stream>>>(
        Wq, Wk, Wv, Wp, wqkvt, wqkvt + (1u << 20), wqkvt + (2u << 20), wpt);

    // merged Q/K/V GEMM: bn 0..7 = Q, 8..15 = K, 16..23 = V
    gemm_qkv<<<dim3(24, MROWS / 128), 256, 0, stream>>>(xb, wqkvt, qws, kws, vtws);

    // grid: x = bh (XCD-local K/V reuse), y = q-block index (heavy-first inside kernel)
    flash_attn<<<dim3(BATCH * NHEAD, SEQ / 128), 256, 0, stream>>>(qws, kws, vtws, attn);

    gemm_proj<<<dim3(NDIM / 128, MROWS / 128), 256, 0, stream>>>(attn, wpt, out, bp);
}

// Round 6
// 219.949 us; speedup vs baseline: 1.7492x; 1.0069x over previous
//
#include <hip/hip_runtime.h>
#include <hip/hip_bf16.h>

#define BATCH 4
#define SEQ   2048
#define DMODEL 1024
#define NHEAD 16
#define HS    64
#define MROWS (BATCH*SEQ)     // 8192
#define KDIM  DMODEL
#define NDIM  DMODEL

typedef short bf16x8 __attribute__((ext_vector_type(8)));
typedef float f32x4  __attribute__((ext_vector_type(4)));
typedef int   i32x2  __attribute__((ext_vector_type(2)));
typedef unsigned u32x4 __attribute__((ext_vector_type(4)));

#if __has_builtin(__builtin_amdgcn_exp2f)
#define EXP2(x) __builtin_amdgcn_exp2f(x)
#else
#define EXP2(x) exp2f(x)
#endif

static __device__ __forceinline__ unsigned short f2bf(float f) {
    union { float f; unsigned int u; } v; v.f = f;
    unsigned int r = (v.u + 0x7fffu + ((v.u >> 16) & 1u)) >> 16;
    return (unsigned short)r;
}

// two f32 -> packed bf16 (RNE) — emits v_cvt_pk_bf16_f32 on gfx950
static __device__ __forceinline__ unsigned int pk_bf16(float a, float b) {
    union { __hip_bfloat162 h; unsigned int u; } c;
    c.h = __float22bfloat162_rn(make_float2(a, b));
    return c.u;
}

// cross-lane half-swaps (gfx950). After pl32: a={a[0:31],b[0:31]}, b={a[32:63],b[32:63]}.
// After pl16: a'={a[0:15],b[0:15],a[32:47],b[32:47]}, b'={a[16:31],b[16:31],a[48:63],b[48:63]}.
static __device__ __forceinline__ void pl32swap(unsigned &a, unsigned &b) {
#if __has_builtin(__builtin_amdgcn_permlane32_swap)
    i32x2 r = __builtin_amdgcn_permlane32_swap((int)a, (int)b, false, false);
    a = (unsigned)r[0]; b = (unsigned)r[1];
#else
    asm volatile("v_permlane32_swap_b32 %0, %1" : "+v"(a), "+v"(b));
#endif
}
static __device__ __forceinline__ void pl16swap(unsigned &a, unsigned &b) {
#if __has_builtin(__builtin_amdgcn_permlane16_swap)
    i32x2 r = __builtin_amdgcn_permlane16_swap((int)a, (int)b, false, false);
    a = (unsigned)r[0]; b = (unsigned)r[1];
#else
    asm volatile("v_permlane16_swap_b32 %0, %1" : "+v"(a), "+v"(b));
#endif
}

// async global->LDS, 16 B per lane. LDS dest must be linear in lane (wave-uniform base + lane*16).
static __device__ __forceinline__ void gl2lds16(const void* g, void* l) {
    __builtin_amdgcn_global_load_lds((const __attribute__((address_space(1))) unsigned int*)g,
                                     (__attribute__((address_space(3))) unsigned int*)l, 16, 0, 0);
}

// ---------------- conversion kernels ----------------
__global__ __launch_bounds__(256) void cvt_bf16(const float* __restrict__ in,
                                                unsigned short* __restrict__ out) {
    int i = blockIdx.x * 256 + threadIdx.x;
    float4 v = ((const float4*)in)[i];
    ushort4 o;
    o.x = f2bf(v.x); o.y = f2bf(v.y); o.z = f2bf(v.z); o.w = f2bf(v.w);
    ((ushort4*)out)[i] = o;
}

// 4x 1024x1024 fp32 -> bf16 transposed, one launch (z selects matrix)
__global__ __launch_bounds__(256) void transpose_cvt4(const float* __restrict__ s0, const float* __restrict__ s1,
                                                      const float* __restrict__ s2, const float* __restrict__ s3,
                                                      unsigned short* __restrict__ d0, unsigned short* __restrict__ d1,
                                                      unsigned short* __restrict__ d2, unsigned short* __restrict__ d3) {
    const float* in; unsigned short* out;
    switch (blockIdx.z) {
        case 0:  in = s0; out = d0; break;
        case 1:  in = s1; out = d1; break;
        case 2:  in = s2; out = d2; break;
        default: in = s3; out = d3; break;
    }
    __shared__ float t[32][33];
    int tx = threadIdx.x, ty = threadIdx.y;          // (32,8)
    int x = blockIdx.x * 32 + tx;
    #pragma unroll
    for (int i = 0; i < 4; ++i) {
        int y = blockIdx.y * 32 + ty + i * 8;
        t[ty + i * 8][tx] = in[(size_t)y * 1024 + x];
    }
    __syncthreads();
    int x2 = blockIdx.y * 32 + tx;
    #pragma unroll
    for (int i = 0; i < 4; ++i) {
        int y2 = blockIdx.x * 32 + ty + i * 8;
        out[(size_t)y2 * 1024 + x2] = f2bf(t[tx][ty + i * 8]);
    }
}

// ---------------- GEMM core (m97 recipe) ----------------
// 128x128 tile, BK=64, global_load_lds width=16, XOR-swizzled LDS (2-way = free).
// Sm is one 32 KB buffer (As|Bs) so epilogues can reuse it for repacking.
// GEMM_DECLS once per kernel (single shared alloc); GEMM_KLOOP(TRANS) per path:
//   TRANS=0 -> C = x·W^T tile (C rows = x-rows);
//   TRANS=1 -> C^T (A-operand = W-frags; acc regs run along W-cols e; lanes = x-rows t).
#define GEMM_DECLS                                                                      \
    __shared__ __align__(16) short Sm[2 * 128 * 64];                                    \
    short* As = Sm;                                                                     \
    short* Bs = Sm + 128 * 64;                                                          \
    const int tid  = threadIdx.x;                                                       \
    const int lane = tid & 63;                                                          \
    const int w    = tid >> 6;                                                          \
    const int wm   = w >> 1, wn = w & 1;                                                \
    const int cc   = lane & 15, quad = lane >> 4;                                       \
    const int bn   = blockIdx.x;                                                        \
    const int bm   = blockIdx.y;                                                        \
    f32x4 acc[4][4] = {};

#define GEMM_KLOOP(TRANS)                                                               \
    {                                                                                   \
    const unsigned short* Ab = A  + (size_t)bm * 128 * KDIM;                            \
    const unsigned short* Bb = Bt + (size_t)bn * 128 * KDIM;                            \
    for (int kb = 0; kb < KDIM; kb += 64) {                                             \
        __syncthreads();                                                                \
        _Pragma("unroll")                                                               \
        for (int i = 0; i < 4; ++i) {                                                   \
            int S = (i * 4 + w) * 64 + lane;                                            \
            int r = S >> 3, g = (S & 7) ^ (r & 7);                                      \
            gl2lds16(Ab + (size_t)r * KDIM + kb + g * 8, (void*)&As[S * 8]);            \
            gl2lds16(Bb + (size_t)r * KDIM + kb + g * 8, (void*)&Bs[S * 8]);            \
        }                                                                               \
        asm volatile("s_waitcnt vmcnt(0)");                                             \
        __syncthreads();                                                                \
        _Pragma("unroll")                                                               \
        for (int kh = 0; kh < 2; ++kh) {                                                \
            bf16x8 xf[4], wf[4];                                                        \
            _Pragma("unroll")                                                           \
            for (int mt = 0; mt < 4; ++mt) {                                            \
                int r = wm * 64 + mt * 16 + cc;                                         \
                xf[mt] = *(const bf16x8*)&As[r * 64 + ((kh * 4 + quad) ^ (r & 7)) * 8]; \
            }                                                                           \
            _Pragma("unroll")                                                           \
            for (int nt = 0; nt < 4; ++nt) {                                            \
                int r = wn * 64 + nt * 16 + cc;                                         \
                wf[nt] = *(const bf16x8*)&Bs[r * 64 + ((kh * 4 + quad) ^ (r & 7)) * 8]; \
            }                                                                           \
            _Pragma("unroll")                                                           \
            for (int mt = 0; mt < 4; ++mt)                                              \
                _Pragma("unroll")                                                       \
                for (int nt = 0; nt < 4; ++nt)                                          \
                    acc[mt][nt] = (TRANS)                                               \
                      ? __builtin_amdgcn_mfma_f32_16x16x32_bf16(wf[nt], xf[mt], acc[mt][nt], 0, 0, 0) \
                      : __builtin_amdgcn_mfma_f32_16x16x32_bf16(xf[mt], wf[nt], acc[mt][nt], 0, 0, 0); \
        }                                                                               \
    }                                                                                   \
    }

// Merged QKV GEMM. Bt = [Wq|Wk|Wv] transposed, contiguous (3072 rows x 1024).
// grid (24, 64): bn 0..7 = Q (transposed acc, scaled), 8..15 = K (transposed acc),
//                16..23 = V (normal acc, V^T repack). Branches are block-uniform.
__global__ __launch_bounds__(256, 3) void gemm_qkv(const unsigned short* __restrict__ A,
                                                   const unsigned short* __restrict__ Bt,
                                                   unsigned short* __restrict__ Qo,
                                                   unsigned short* __restrict__ Ko,
                                                   unsigned short* __restrict__ Vo) {
    GEMM_DECLS
    if (bn < 16) {
        GEMM_KLOOP(1)
        // lane holds e = wn*64+nt*16+quad*4+r, t = wm*64+mt*16+cc. Repack via LDS,
        // fully-coalesced 16B/lane stores to (B,H,T,hs).
        const bool isK = bn >= 8;
        const float scale = isK ? 1.0f : 0.125f * 1.44269504f;   // hs^-0.5 * log2(e) for Q
        unsigned short* outp = isK ? Ko : Qo;
        __syncthreads();     // staging reads done; reuse Sm as [t 128][e 128] shorts
        #pragma unroll
        for (int mt = 0; mt < 4; ++mt) {
            #pragma unroll
            for (int nt = 0; nt < 4; ++nt) {
                int t  = wm * 64 + mt * 16 + cc;
                int e0 = wn * 64 + nt * 16 + quad * 4;
                uint2 pu;
                pu.x = pk_bf16(acc[mt][nt][0] * scale, acc[mt][nt][1] * scale);
                pu.y = pk_bf16(acc[mt][nt][2] * scale, acc[mt][nt][3] * scale);
                int sp = (e0 >> 2) ^ (t & 31);
                *(uint2*)&Sm[t * 128 + sp * 4] = pu;
            }
        }
        __syncthreads();
        const int h0 = (bn & 7) * 2;
        const int b  = bm >> 4;
        const int t0 = (bm & 15) * 128;
        #pragma unroll
        for (int i = 0; i < 8; ++i) {
            int s = i * 256 + tid;
            int t = s >> 4, g = s & 15;                 // 16-lane groups share t
            int sp0 = (2 * g)     ^ (t & 31);
            int sp1 = (2 * g + 1) ^ (t & 31);
            uint2 lo = *(const uint2*)&Sm[t * 128 + sp0 * 4];
            uint2 hi = *(const uint2*)&Sm[t * 128 + sp1 * 4];
            int h = h0 + (g >> 3), e = (g & 7) * 8;
            size_t addr = ((size_t)(b * NHEAD + h) * SEQ + t0 + t) * HS + e;
            uint4 u; u.x = lo.x; u.y = lo.y; u.z = hi.x; u.w = hi.y;
            *(uint4*)&outp[addr] = u;
        }
    } else {
        GEMM_KLOOP(0)
        // V: repack through LDS, store V^T (B,H,hs,T) coalesced.
        __syncthreads();
        #pragma unroll
        for (int mt = 0; mt < 4; ++mt) {
            #pragma unroll
            for (int nt = 0; nt < 4; ++nt) {
                int n    = wn * 64 + nt * 16 + cc;            // col in tile (e-dim)
                int slot = wm * 16 + mt * 4 + quad;           // t/4 (4 rows per 8B slot)
                int sp   = slot ^ (n & 31);
                uint2 pu;
                pu.x = pk_bf16(acc[mt][nt][0], acc[mt][nt][1]);
                pu.y = pk_bf16(acc[mt][nt][2], acc[mt][nt][3]);
                *(uint2*)&Sm[n * 128 + sp * 4] = pu;
            }
        }
        __syncthreads();
        const int h0 = (bn & 7) * 2;
        const int b  = bm >> 4;
        const int t0 = (bm & 15) * 128;
        #pragma unroll
        for (int i = 0; i < 8; ++i) {
            int s = i * 256 + tid;
            int n = s >> 4, g = s & 15;
            int sp0 = (2 * g)     ^ (n & 31);
            int sp1 = (2 * g + 1) ^ (n & 31);
            uint2 lo = *(const uint2*)&Sm[n * 128 + sp0 * 4];
            uint2 hi = *(const uint2*)&Sm[n * 128 + sp1 * 4];
            int h = h0 + (n >> 6), e = n & 63;
            size_t addr = ((size_t)((b * NHEAD + h) * HS + e)) * SEQ + t0 + g * 8;
            uint4 u; u.x = lo.x; u.y = lo.y; u.z = hi.x; u.w = hi.y;
            *(uint4*)&Vo[addr] = u;
        }
    }
}

// Output projection: C[M,N] fp32 = A @ Wp (+bias)
__global__ __launch_bounds__(256, 3) void gemm_proj(const unsigned short* __restrict__ A,
                                                    const unsigned short* __restrict__ Bt,
                                                    float* __restrict__ Cout,
                                                    const float* __restrict__ bias) {
    GEMM_DECLS
    GEMM_KLOOP(0)
    #pragma unroll
    for (int mt = 0; mt < 4; ++mt) {
        #pragma unroll
        for (int nt = 0; nt < 4; ++nt) {
            f32x4 a = acc[mt][nt];
            int gn  = bn * 128 + wn * 64 + nt * 16 + cc;
            int gm0 = bm * 128 + wm * 64 + mt * 16 + quad * 4;
            #pragma unroll
            for (int r = 0; r < 4; ++r)
                Cout[(size_t)(gm0 + r) * NDIM + gn] = a[r] + bias[gn];
        }
    }
}

// ---------------- flash attention (transposed-S, in-register P, pipelined groups) ----
// Q,K: (B,H,T,hs) bf16 (Q pre-scaled by 0.125*log2e); Vt: (B,H,hs,T) bf16; O: (B,T,H*hs) bf16.
// Grid: x = bh (fast dim -> same bh pinned to one XCD via id%8), y = q-block (heavy-first).
// S^T = K*Q^T -> per lane: q = lane&15, 32 key-scores in regs.  O^T = V*P^T.
// r11: T12 in-register P (cvtpk + permlane32/16 swaps), bank conflicts -> 0.
// r13: fused per-32-key-group loop, single-buffer K/V (32 KB), (256,3), VGPR 68.
// r14 (this round): TWO-STAGE GROUP PIPELINE (T15 mechanism). r13 showed occupancy
//   24% with dur flat at 60us: the limit is within-wave serialization (QK->exp->pack
//   ->PV is a strict chain; MFMA 1400cyc + VALU 1900cyc ADD instead of overlapping;
//   MfmaUtil 26 + VALUBusy 46 both ~= their share of a serial 4200cyc trip).
//   MFMA issue is non-blocking, so issuing QK MFMAs of group g+1 BEFORE the softmax
//   VALU of group g lets the matrix pipe grind under the VALU work. Ping-pong two
//   STATIC score buffers (rule #20: no runtime-indexed regs):
//     QK(0,s0); QK(1,s1); SMPV(0,s0); QK(2,s0'); SMPV(1,s1); QK(3,s1'); SMPV(2,s0);
//     SMPV(3,s1)   [each guarded by wave-uniform gact = diagonal group count]
//   Live state +16 f32 regs -> ~100 VGPR, still under the (256,3) ~170 cap.
//   Spill tripwire: WRITE_SIZE must stay ~16 MB (r9: 92 MB, r12: 309 MB = spills).
__global__ __launch_bounds__(256, 3) void flash_attn(const unsigned short* __restrict__ Q,
                                                     const unsigned short* __restrict__ K,
                                                     const unsigned short* __restrict__ Vt,
                                                     unsigned short* __restrict__ O) {
    __shared__ __align__(16) short Ks[128 * 64];  // (key,hs) row=8 groups, slot g^(r&7)
    __shared__ __align__(16) short Vs[64 * 128];  // (d,key)  row=16 groups, slot g^(d&15)

    const int tid  = threadIdx.x;
    const int lane = tid & 63;
    const int w    = tid >> 6;
    const int cc   = lane & 15, quad = lane >> 4;
    const int bh   = blockIdx.x;                                     // 0..63
    const int qblk = ((int)gridDim.y - 1 - (int)blockIdx.y) * 128;   // heavy blocks first
    const int b    = bh >> 4, h = bh & 15;

    const unsigned short* Qb = Q  + (size_t)bh * SEQ * HS;
    const unsigned short* Kb = K  + (size_t)bh * SEQ * HS;
    const unsigned short* Vb = Vt + (size_t)bh * HS * SEQ;

    // Q fragments (B-operand), held in registers
    bf16x8 qf[2][2];
    #pragma unroll
    for (int qt = 0; qt < 2; ++qt) {
        int qg = qblk + w * 32 + qt * 16;
        const unsigned short* qp = Qb + (size_t)(qg + cc) * HS;
        qf[qt][0] = *(const bf16x8*)(qp + quad * 8);
        qf[qt][1] = *(const bf16x8*)(qp + 32 + quad * 8);
    }

    bf16x8 onesv;
    #pragma unroll
    for (int j = 0; j < 8; ++j) onesv[j] = (short)0x3F80;   // bf16 1.0

    f32x4 o[2][4] = {};
    f32x4 lacc[2] = {};
    const f32x4 zero = {};

    // 8 global_load_lds per wave per tile (4 K + 4 V), LDS dest linear in lane
#define STAGE_KV(kb_)                                                                   \
    _Pragma("unroll")                                                                   \
    for (int i = 0; i < 4; ++i) {                                                       \
        int S = (i * 4 + w) * 64 + lane;                                                \
        {   /* K tile: 128 keys x 64 hs */                                              \
            int r = S >> 3, g = (S & 7) ^ (r & 7);                                      \
            gl2lds16(Kb + (size_t)((kb_) + r) * HS + g * 8, (void*)&Ks[S * 8]);         \
        }                                                                               \
        {   /* V tile: 64 d x 128 keys */                                               \
            int d = S >> 4, g = (S & 15) ^ (d & 15);                                    \
            gl2lds16(Vb + (size_t)d * SEQ + (kb_) + g * 8, (void*)&Vs[S * 8]);          \
        }                                                                               \
    }

    // QK^T for one 32-key group -> sdst[qt][ktl] (8 MFMA)
#define QK_GROUP(g_, sdst)                                                              \
    {                                                                                   \
        _Pragma("unroll")                                                               \
        for (int ktl = 0; ktl < 2; ++ktl) {                                             \
            int r = ((g_) * 2 + ktl) * 16 + cc;                                         \
            bf16x8 kf0 = *(const bf16x8*)&Ks[r * 64 + ((quad)     ^ (r & 7)) * 8];      \
            bf16x8 kf1 = *(const bf16x8*)&Ks[r * 64 + ((4 + quad) ^ (r & 7)) * 8];      \
            sdst[0][ktl] = __builtin_amdgcn_mfma_f32_16x16x32_bf16(kf0, qf[0][0], zero,        0, 0, 0); \
            sdst[0][ktl] = __builtin_amdgcn_mfma_f32_16x16x32_bf16(kf1, qf[0][1], sdst[0][ktl], 0, 0, 0); \
            sdst[1][ktl] = __builtin_amdgcn_mfma_f32_16x16x32_bf16(kf0, qf[1][0], zero,        0, 0, 0); \
            sdst[1][ktl] = __builtin_amdgcn_mfma_f32_16x16x32_bf16(kf1, qf[1][1], sdst[1][ktl], 0, 0, 0); \
        }                                                                               \
    }

    // mask+exp2+pack (in-register, T12) then lacc/PV MFMAs for one group
#define SMPV(g_, s_)                                                                    \
    {                                                                                   \
        bf16x8 pb[2];                                                                   \
        _Pragma("unroll")                                                               \
        for (int qt = 0; qt < 2; ++qt) {                                                \
            const int qg = qblk + w * 32 + qt * 16;                                     \
            if (kb + (g_) * 32 + 31 > qg) {           /* group overlaps diagonal */     \
                _Pragma("unroll")                                                       \
                for (int ktl = 0; ktl < 2; ++ktl)                                       \
                    _Pragma("unroll")                                                   \
                    for (int r = 0; r < 4; ++r)                                         \
                        if (kb + ((g_) * 2 + ktl) * 16 + quad * 4 + r > qg + cc)        \
                            s_[qt][ktl][r] = -1e30f;                                    \
            }                                                                           \
            _Pragma("unroll")                                                           \
            for (int ktl = 0; ktl < 2; ++ktl) {                                         \
                s_[qt][ktl][0] = EXP2(s_[qt][ktl][0]);                                  \
                s_[qt][ktl][1] = EXP2(s_[qt][ktl][1]);                                  \
                s_[qt][ktl][2] = EXP2(s_[qt][ktl][2]);                                  \
                s_[qt][ktl][3] = EXP2(s_[qt][ktl][3]);                                  \
            }                                                                           \
            unsigned a0 = pk_bf16(s_[qt][0][0], s_[qt][0][1]);                          \
            unsigned a1 = pk_bf16(s_[qt][0][2], s_[qt][0][3]);                          \
            unsigned b0 = pk_bf16(s_[qt][1][0], s_[qt][1][1]);                          \
            unsigned b1 = pk_bf16(s_[qt][1][2], s_[qt][1][3]);                          \
            pl32swap(a0, b0); pl16swap(a0, b0);   /* a0 = dword j(0,1), b0 = j(4,5) */  \
            pl32swap(a1, b1); pl16swap(a1, b1);   /* a1 = dword j(2,3), b1 = j(6,7) */  \
            u32x4 pw; pw[0] = a0; pw[1] = a1; pw[2] = b0; pw[3] = b1;                   \
            pb[qt] = __builtin_bit_cast(bf16x8, pw);                                    \
        }                                                                               \
        lacc[0] = __builtin_amdgcn_mfma_f32_16x16x32_bf16(onesv, pb[0], lacc[0], 0, 0, 0); \
        lacc[1] = __builtin_amdgcn_mfma_f32_16x16x32_bf16(onesv, pb[1], lacc[1], 0, 0, 0); \
        _Pragma("unroll")                                                               \
        for (int nt = 0; nt < 4; ++nt) {                                                \
            int d = nt * 16 + cc;                                                       \
            bf16x8 vf = *(const bf16x8*)&Vs[d * 128 + (((g_) * 4 + quad) ^ (d & 15)) * 8]; \
            o[0][nt] = __builtin_amdgcn_mfma_f32_16x16x32_bf16(vf, pb[0], o[0][nt], 0, 0, 0); \
            o[1][nt] = __builtin_amdgcn_mfma_f32_16x16x32_bf16(vf, pb[1], o[1][nt], 0, 0, 0); \
        }                                                                               \
    }

    const int trips = qblk / 128 + 1;
    for (int it = 0; it < trips; ++it) {
        const int kb = it * 128;

        STAGE_KV(kb)
        asm volatile("s_waitcnt vmcnt(0)" ::: "memory");
        __builtin_amdgcn_s_barrier();                // tile resident for all waves
        __builtin_amdgcn_sched_barrier(0);

        // active group count: all 4 except the diagonal trip, where groups > w are
        // fully causal-masked (wave-uniform)
        const int gact = (kb == qblk) ? (w + 1) : 4;

        // two-stage pipeline over groups, static ping-pong buffers s0/s1:
        // QK of group g+1 issues BEFORE softmax/PV of group g -> MFMA pipe grinds
        // under the exp/pack VALU chain.
        f32x4 s0[2][2], s1[2][2];
        QK_GROUP(0, s0)                              // g=0 always active (w >= 0)
        if (1 < gact) QK_GROUP(1, s1)
        SMPV(0, s0)
        if (2 < gact) QK_GROUP(2, s0)
        if (1 < gact) SMPV(1, s1)
        if (3 < gact) QK_GROUP(3, s1)
        if (2 < gact) SMPV(2, s0)
        if (3 < gact) SMPV(3, s1)

        __builtin_amdgcn_sched_barrier(0);
        __builtin_amdgcn_s_barrier();                // all waves done reading before restage
    }

    // epilogue: lane holds O^T[d = nt*16 + quad*4 + r][q = cc]; l[q] = lacc[qt][any reg]
    #pragma unroll
    for (int qt = 0; qt < 2; ++qt) {
        int qg = qblk + w * 32 + qt * 16;
        float inv = 1.0f / lacc[qt][0];
        size_t base = ((size_t)b * SEQ + qg + cc) * DMODEL + h * HS;
        #pragma unroll
        for (int nt = 0; nt < 4; ++nt) {
            ushort4 u;
            u.x = f2bf(o[qt][nt][0] * inv);
            u.y = f2bf(o[qt][nt][1] * inv);
            u.z = f2bf(o[qt][nt][2] * inv);
            u.w = f2bf(o[qt][nt][3] * inv);
            *(ushort4*)&O[base + nt * 16 + quad * 4] = u;
        }
    }
}

// ---------------- launch ----------------
extern "C" void kernel_launch(void* const* d_in, const int* in_sizes, int n_in,
                              void* d_out, int out_size, void* d_ws, size_t ws_size,
                              hipStream_t stream) {
    const float* x  = (const float*)d_in[0];
    const float* Wq = (const float*)d_in[1];
    const float* Wk = (const float*)d_in[2];
    const float* Wv = (const float*)d_in[3];
    const float* Wp = (const float*)d_in[4];
    const float* bp = (const float*)d_in[5];
    float* out = (float*)d_out;

    char* ws = (char*)d_ws;
    unsigned short* xb    = (unsigned short*)(ws);                      // 16 MiB
    unsigned short* wqkvt = (unsigned short*)(ws + (16u << 20));        // 6 MiB (Q|K|V transposed)
    unsigned short* wpt   = (unsigned short*)(ws + (22u << 20));        // 2 MiB
    unsigned short* qws   = (unsigned short*)(ws + (24u << 20));        // 16 MiB
    unsigned short* kws   = (unsigned short*)(ws + (40u << 20));        // 16 MiB
    unsigned short* vtws  = (unsigned short*)(ws + (56u << 20));        // 16 MiB
    unsigned short* attn  = (unsigned short*)(ws + (72u << 20));        // 16 MiB

    cvt_bf16<<<MROWS * DMODEL / 1024, 256, 0, stream>>>(x, xb);

    transpose_cvt4<<<dim3(32, 32, 4), dim3(32, 8), 0, stream>>>(
        Wq, Wk, Wv, Wp, wqkvt, wqkvt + (1u << 20), wqkvt + (2u << 20), wpt);

    // merged Q/K/V GEMM: bn 0..7 = Q, 8..15 = K, 16..23 = V
    gemm_qkv<<<dim3(24, MROWS / 128), 256, 0, stream>>>(xb, wqkvt, qws, kws, vtws);

    // grid: x = bh (XCD-local K/V reuse), y = q-block index (heavy-first inside kernel)
    flash_attn<<<dim3(BATCH * NHEAD, SEQ / 128), 256, 0, stream>>>(qws, kws, vtws, attn);

    gemm_proj<<<dim3(NDIM / 128, MROWS / 128), 256, 0, stream>>>(attn, wpt, out, bp);
}